// Round 1
// baseline (83278.644 us; speedup 1.0000x reference)
//
#include <hip/hip_runtime.h>
#include <math.h>

#define NB_ENC 64
#define TSTEPS 4096
#define DIM 1024
#define GDIM 4096

__device__ __forceinline__ float sigmoidf_(float x) {
    return 1.0f / (1.0f + expf(-x));
}

// ---------------- GEMM: C[M,N] = A[M,K] @ B[N,K]^T (+bias1+bias2) (+= if ACCUM)
template<bool ACCUM, bool BIAS>
__global__ __launch_bounds__(256)
void gemm_nt(const float* __restrict__ A, const float* __restrict__ B,
             const float* __restrict__ bias1, const float* __restrict__ bias2,
             float* __restrict__ C, int M, int N, int K)
{
    __shared__ float As[16][65];
    __shared__ float Bs[16][65];
    const int tx = threadIdx.x & 15;
    const int ty = threadIdx.x >> 4;
    const int m0 = blockIdx.y * 64;
    const int n0 = blockIdx.x * 64;
    const int lrow = threadIdx.x >> 2;       // 0..63
    const int lk4  = (threadIdx.x & 3) * 4;  // 0,4,8,12

    float acc[4][4] = {};
    for (int k0 = 0; k0 < K; k0 += 16) {
        {
            int gm = m0 + lrow;
            float4 v = make_float4(0.f, 0.f, 0.f, 0.f);
            if (gm < M) v = *(const float4*)(A + (size_t)gm * K + k0 + lk4);
            As[lk4 + 0][lrow] = v.x; As[lk4 + 1][lrow] = v.y;
            As[lk4 + 2][lrow] = v.z; As[lk4 + 3][lrow] = v.w;
            int gn = n0 + lrow;
            float4 w = *(const float4*)(B + (size_t)gn * K + k0 + lk4);
            Bs[lk4 + 0][lrow] = w.x; Bs[lk4 + 1][lrow] = w.y;
            Bs[lk4 + 2][lrow] = w.z; Bs[lk4 + 3][lrow] = w.w;
        }
        __syncthreads();
        #pragma unroll
        for (int kk = 0; kk < 16; ++kk) {
            float a[4], b[4];
            #pragma unroll
            for (int i = 0; i < 4; ++i) a[i] = As[kk][ty * 4 + i];
            #pragma unroll
            for (int j = 0; j < 4; ++j) b[j] = Bs[kk][tx * 4 + j];
            #pragma unroll
            for (int i = 0; i < 4; ++i)
                #pragma unroll
                for (int j = 0; j < 4; ++j)
                    acc[i][j] = fmaf(a[i], b[j], acc[i][j]);
        }
        __syncthreads();
    }
    #pragma unroll
    for (int i = 0; i < 4; ++i) {
        int gm = m0 + ty * 4 + i;
        if (gm >= M) continue;
        #pragma unroll
        for (int j = 0; j < 4; ++j) {
            int gn = n0 + tx * 4 + j;
            float v = acc[i][j];
            if (BIAS) v += bias1[gn] + bias2[gn];
            size_t idx = (size_t)gm * N + gn;
            if (ACCUM) v += C[idx];
            C[idx] = v;
        }
    }
}

// ---------------- Encoder sequential scan: persistent, grid barrier per step.
// 64 blocks x 256 threads. Block b owns h-channels [b*16, b*16+16).
// Thread t: gate-row r = t>>2 (0..63), k-chunk sub = t&3 (256 floats each).
// gate row global = q*1024 + hbase + hi, q = r>>4, hi = r&15.
__global__ __launch_bounds__(256)
void encoder_scan(const float* __restrict__ Xg,   // [4096][4096] x@Wih.T + biases
                  const float* __restrict__ Whh,  // [4096][1024]
                  float* __restrict__ signal,     // [4096][1024]
                  float* __restrict__ hbuf,       // [1024], pre-zeroed
                  unsigned* __restrict__ counter) // pre-zeroed
{
    const int b = blockIdx.x;
    const int t = threadIdx.x;
    const int hbase = b * 16;
    const int r = t >> 2, sub = t & 3;
    const int q = r >> 4, hi = r & 15;
    const int grow = q * 1024 + hbase + hi;
    const float* wrow = Whh + (size_t)grow * 1024 + sub * 256;
    const float* hvec = hbuf + sub * 256;

    __shared__ float gl[4][16];
    __shared__ float cs[16];
    if (t < 16) cs[t] = 0.0f;
    __syncthreads();

    for (int step = 0; step < TSTEPS; ++step) {
        float s = 0.0f;
        #pragma unroll 8
        for (int k = 0; k < 256; k += 4) {
            float4 w  = *(const float4*)(wrow + k);
            float4 h4 = *(const float4*)(hvec + k);
            s = fmaf(w.x, h4.x, s); s = fmaf(w.y, h4.y, s);
            s = fmaf(w.z, h4.z, s); s = fmaf(w.w, h4.w, s);
        }
        s += __shfl_xor(s, 1);
        s += __shfl_xor(s, 2);
        if (sub == 0) gl[q][hi] = s + Xg[(size_t)step * GDIM + grow];
        __syncthreads();
        if (t < 16) {
            float iv = sigmoidf_(gl[0][t]);
            float fv = sigmoidf_(gl[1][t]);
            float gv = tanhf(gl[2][t]);
            float ov = sigmoidf_(gl[3][t]);
            float c = fmaf(fv, cs[t], iv * gv);
            cs[t] = c;
            float h = ov * tanhf(c);
            hbuf[hbase + t] = h;
            signal[(size_t)step * DIM + hbase + t] = h;
        }
        __syncthreads();
        if (t == 0) {
            __threadfence();
            __hip_atomic_fetch_add(counter, 1u, __ATOMIC_RELEASE, __HIP_MEMORY_SCOPE_AGENT);
            const unsigned target = (unsigned)NB_ENC * (unsigned)(step + 1);
            while (__hip_atomic_load(counter, __ATOMIC_ACQUIRE, __HIP_MEMORY_SCOPE_AGENT) < target) {
                __builtin_amdgcn_s_sleep(2);
            }
        }
        __syncthreads();
    }
}

// ---------------- Decoder: c-recurrence is elementwise per channel -> 1024
// independent scans. decoded[t] = o*tanh(c); accumulate sum of squared error.
__global__ __launch_bounds__(256)
void decoder_scan(const float* __restrict__ G,    // [4095][4096] full gate preacts
                  const float* __restrict__ inp,  // [4096][1024]
                  float* __restrict__ mse_acc)
{
    const int j = blockIdx.x * 256 + threadIdx.x; // 0..1023
    float c = 0.f, acc = 0.f;
    for (int tstep = 0; tstep < TSTEPS - 1; ++tstep) {
        const float* g = G + (size_t)tstep * GDIM;
        float iv = sigmoidf_(g[j]);
        float fv = sigmoidf_(g[j + 1024]);
        float gv = tanhf(g[j + 2048]);
        float ov = sigmoidf_(g[j + 3072]);
        c = fmaf(fv, c, iv * gv);
        float d = ov * tanhf(c);
        float diff = d - inp[(size_t)(tstep + 1) * DIM + j];
        acc = fmaf(diff, diff, acc);
    }
    #pragma unroll
    for (int off = 32; off >= 1; off >>= 1) acc += __shfl_xor(acc, off);
    if ((threadIdx.x & 63) == 0) atomicAdd(mse_acc, acc);
}

__global__ __launch_bounds__(256)
void l1_reduce(const float* __restrict__ x, float* __restrict__ acc)
{
    const size_t n4 = (size_t)TSTEPS * DIM / 4;
    size_t tid = (size_t)blockIdx.x * 256 + threadIdx.x;
    size_t stride = (size_t)gridDim.x * 256;
    float s = 0.f;
    for (size_t i = tid; i < n4; i += stride) {
        float4 v = ((const float4*)x)[i];
        s += fabsf(v.x) + fabsf(v.y) + fabsf(v.z) + fabsf(v.w);
    }
    #pragma unroll
    for (int off = 32; off >= 1; off >>= 1) s += __shfl_xor(s, off);
    if ((threadIdx.x & 63) == 0) atomicAdd(acc, s);
}

__global__ void finalize(const float* __restrict__ scal, float* __restrict__ out)
{
    float mse = scal[1] / ((float)(TSTEPS - 1) * (float)DIM);
    float l1  = scal[2] / ((float)TSTEPS * (float)DIM);
    out[0] = mse + 0.25f * l1;
    out[1] = mse;
    out[2] = l1;
}

extern "C" void kernel_launch(void* const* d_in, const int* in_sizes, int n_in,
                              void* d_out, int out_size, void* d_ws, size_t ws_size,
                              hipStream_t stream)
{
    const float* inputs  = (const float*)d_in[0];
    const float* enc_Wih = (const float*)d_in[1];
    const float* enc_Whh = (const float*)d_in[2];
    const float* enc_bih = (const float*)d_in[3];
    const float* enc_bhh = (const float*)d_in[4];
    const float* dec_Wih = (const float*)d_in[5];
    const float* dec_Whh = (const float*)d_in[6];
    const float* dec_bih = (const float*)d_in[7];
    const float* dec_bhh = (const float*)d_in[8];
    float* out = (float*)d_out;

    float* ws = (float*)d_ws;
    float* gates  = ws;                        // 4096*4096 floats (Xenc then Gdec)
    float* signal = ws + (size_t)16777216;     // 4096*1024
    float* hbuf   = ws + (size_t)20971520;     // 1024
    float* scal   = ws + (size_t)20972544;     // [counter(u32), mse, l1, ...]
    unsigned* counter = (unsigned*)scal;
    float* mse_acc = scal + 1;
    float* l1_acc  = scal + 2;

    // zero hbuf + counter + accumulators (contiguous region)
    hipMemsetAsync(hbuf, 0, (1024 + 8) * sizeof(float), stream);

    dim3 b256(256);
    // Xenc = inputs @ enc_Wih.T + enc_bih + enc_bhh
    gemm_nt<false, true><<<dim3(64, 64), b256, 0, stream>>>(
        inputs, enc_Wih, enc_bih, enc_bhh, gates, 4096, 4096, 1024);
    // sequential encoder
    encoder_scan<<<dim3(NB_ENC), b256, 0, stream>>>(
        gates, enc_Whh, signal, hbuf, counter);
    // Gdec = signal[1:] @ dec_Wih.T + dec_bih + dec_bhh
    gemm_nt<false, true><<<dim3(64, 64), b256, 0, stream>>>(
        signal + DIM, dec_Wih, dec_bih, dec_bhh, gates, 4095, 4096, 1024);
    // Gdec += inputs[:-1] @ dec_Whh.T
    gemm_nt<true, false><<<dim3(64, 64), b256, 0, stream>>>(
        inputs, dec_Whh, nullptr, nullptr, gates, 4095, 4096, 1024);
    // decoder elementwise scan + mse
    decoder_scan<<<dim3(4), b256, 0, stream>>>(gates, inputs, mse_acc);
    // l1 over signal
    l1_reduce<<<dim3(256), b256, 0, stream>>>(signal, l1_acc);
    finalize<<<dim3(1), dim3(1), 0, stream>>>(scal, out);
}

// Round 2
// 58173.730 us; speedup vs baseline: 1.4316x; 1.4316x over previous
//
#include <hip/hip_runtime.h>
#include <math.h>

#define TSTEPS 4096
#define DIM 1024
#define GDIM 4096
#define ENC_NB 64

__device__ __forceinline__ float sigmoidf_(float x) {
    return 1.0f / (1.0f + expf(-x));
}

// ---------------- GEMM: C[M,N] = A[M,K] @ B[N,K]^T (+bias1+bias2) (+= if ACCUM)
template<bool ACCUM, bool BIAS>
__global__ __launch_bounds__(256)
void gemm_nt(const float* __restrict__ A, const float* __restrict__ B,
             const float* __restrict__ bias1, const float* __restrict__ bias2,
             float* __restrict__ C, int M, int N, int K)
{
    __shared__ float As[16][65];
    __shared__ float Bs[16][65];
    const int tx = threadIdx.x & 15;
    const int ty = threadIdx.x >> 4;
    const int m0 = blockIdx.y * 64;
    const int n0 = blockIdx.x * 64;
    const int lrow = threadIdx.x >> 2;       // 0..63
    const int lk4  = (threadIdx.x & 3) * 4;  // 0,4,8,12

    float acc[4][4] = {};
    for (int k0 = 0; k0 < K; k0 += 16) {
        {
            int gm = m0 + lrow;
            float4 v = make_float4(0.f, 0.f, 0.f, 0.f);
            if (gm < M) v = *(const float4*)(A + (size_t)gm * K + k0 + lk4);
            As[lk4 + 0][lrow] = v.x; As[lk4 + 1][lrow] = v.y;
            As[lk4 + 2][lrow] = v.z; As[lk4 + 3][lrow] = v.w;
            int gn = n0 + lrow;
            float4 w = *(const float4*)(B + (size_t)gn * K + k0 + lk4);
            Bs[lk4 + 0][lrow] = w.x; Bs[lk4 + 1][lrow] = w.y;
            Bs[lk4 + 2][lrow] = w.z; Bs[lk4 + 3][lrow] = w.w;
        }
        __syncthreads();
        #pragma unroll
        for (int kk = 0; kk < 16; ++kk) {
            float a[4], b[4];
            #pragma unroll
            for (int i = 0; i < 4; ++i) a[i] = As[kk][ty * 4 + i];
            #pragma unroll
            for (int j = 0; j < 4; ++j) b[j] = Bs[kk][tx * 4 + j];
            #pragma unroll
            for (int i = 0; i < 4; ++i)
                #pragma unroll
                for (int j = 0; j < 4; ++j)
                    acc[i][j] = fmaf(a[i], b[j], acc[i][j]);
        }
        __syncthreads();
    }
    #pragma unroll
    for (int i = 0; i < 4; ++i) {
        int gm = m0 + ty * 4 + i;
        if (gm >= M) continue;
        #pragma unroll
        for (int j = 0; j < 4; ++j) {
            int gn = n0 + tx * 4 + j;
            float v = acc[i][j];
            if (BIAS) v += bias1[gn] + bias2[gn];
            size_t idx = (size_t)gm * N + gn;
            if (ACCUM) v += C[idx];
            C[idx] = v;
        }
    }
}

// ---------------- Encoder sequential scan: persistent, per-block flag barrier.
// 64 blocks x 256 threads. Block b owns h-channels [b*16, b*16+16).
// Thread t: gate-row r = t>>2 (0..63), k-quarter sub = t&3 (256 floats each).
// h published into double-buffered padded slots (128B/block), tags monotonic.
__global__ __launch_bounds__(256)
void encoder_scan(const float* __restrict__ Xg,   // [4096][4096] x@Wih.T + biases
                  const float* __restrict__ Whh,  // [4096][1024]
                  float* __restrict__ signal,     // [4096][1024]
                  float* __restrict__ hsl,        // [2][ENC_NB*32] zeroed
                  unsigned* __restrict__ tags)    // [ENC_NB*32] zeroed
{
    const int b = blockIdx.x;
    const int t = threadIdx.x;
    const int hbase = b * 16;
    const int r = t >> 2, sub = t & 3;
    const int q = r >> 4, hi = r & 15;
    const int grow = q * 1024 + hbase + hi;
    const float* wrow = Whh + (size_t)grow * 1024 + sub * 256;

    __shared__ float hls[4 * 260];   // stride 260 -> k-quarters on disjoint banks
    __shared__ float gl[4][16];
    __shared__ float cs[16];
    if (t < 16) cs[t] = 0.f;
    __syncthreads();

    // gather assignment: thread t pulls 4 h values from publisher block gj
    const int gj = t >> 2;
    const int gq = t & 3;
    const int hidx = gj * 16 + gq * 4;       // global h index of first element
    const int lc = hidx >> 8, lo = hidx & 255;

    for (int step = 0; step < TSTEPS; ++step) {
        // prefetch this step's Xg (independent of barrier; hides under poll)
        float xg = 0.f;
        if (sub == 0) xg = Xg[(size_t)step * GDIM + grow];

        // wait for h^step: 64 parallel tag polls, no contention
        if (t < 64) {
            const unsigned tgt = (unsigned)step;
            while (true) {
                unsigned tg = __hip_atomic_load(tags + t * 32, __ATOMIC_RELAXED,
                                                __HIP_MEMORY_SCOPE_AGENT);
                if (__all(tg >= tgt)) break;
                __builtin_amdgcn_s_sleep(1);
            }
            __threadfence();
        }
        __syncthreads();

        // gather h^step -> LDS (cache-bypassing 8B loads)
        {
            const float* p = hsl + (size_t)(step & 1) * (ENC_NB * 32) + gj * 32 + gq * 4;
            unsigned long long v0 = __hip_atomic_load((const unsigned long long*)p,
                                        __ATOMIC_RELAXED, __HIP_MEMORY_SCOPE_AGENT);
            unsigned long long v1 = __hip_atomic_load((const unsigned long long*)(p + 2),
                                        __ATOMIC_RELAXED, __HIP_MEMORY_SCOPE_AGENT);
            float2 f0 = __builtin_bit_cast(float2, v0);
            float2 f1 = __builtin_bit_cast(float2, v1);
            hls[lc * 260 + lo + 0] = f0.x;
            hls[lc * 260 + lo + 1] = f0.y;
            hls[lc * 260 + lo + 2] = f1.x;
            hls[lc * 260 + lo + 3] = f1.y;
        }
        __syncthreads();

        // dot: row grow, quarter sub
        float s = 0.f;
        const float* hv = hls + sub * 260;
        #pragma unroll 8
        for (int k = 0; k < 256; k += 4) {
            float4 w  = *(const float4*)(wrow + k);
            float4 h4 = *(const float4*)(hv + k);
            s = fmaf(w.x, h4.x, s); s = fmaf(w.y, h4.y, s);
            s = fmaf(w.z, h4.z, s); s = fmaf(w.w, h4.w, s);
        }
        s += __shfl_xor(s, 1);
        s += __shfl_xor(s, 2);
        if (sub == 0) gl[q][hi] = s + xg;
        __syncthreads();

        if (t < 16) {
            float iv = sigmoidf_(gl[0][t]);
            float fv = sigmoidf_(gl[1][t]);
            float gv = tanhf(gl[2][t]);
            float ov = sigmoidf_(gl[3][t]);
            float c = fmaf(fv, cs[t], iv * gv);
            cs[t] = c;
            float h = ov * tanhf(c);
            float* dst = hsl + (size_t)((step + 1) & 1) * (ENC_NB * 32) + b * 32 + t;
            __hip_atomic_store(dst, h, __ATOMIC_RELAXED, __HIP_MEMORY_SCOPE_AGENT);
            signal[(size_t)step * DIM + hbase + t] = h;
        }
        __syncthreads();   // h stores complete (vmcnt drained) before tag release

        if (t == 0) {
            __threadfence();
            __hip_atomic_store(tags + b * 32, (unsigned)(step + 1),
                               __ATOMIC_RELEASE, __HIP_MEMORY_SCOPE_AGENT);
        }
    }
}

// ---------------- Decoder: c-recurrence is elementwise per channel -> 1024
// independent scans. decoded[t] = o*tanh(c); accumulate sum of squared error.
__global__ __launch_bounds__(256)
void decoder_scan(const float* __restrict__ G,    // [4095][4096] full gate preacts
                  const float* __restrict__ inp,  // [4096][1024]
                  float* __restrict__ mse_acc)
{
    const int j = blockIdx.x * 256 + threadIdx.x; // 0..1023
    float c = 0.f, acc = 0.f;
    for (int tstep = 0; tstep < TSTEPS - 1; ++tstep) {
        const float* g = G + (size_t)tstep * GDIM;
        float iv = sigmoidf_(g[j]);
        float fv = sigmoidf_(g[j + 1024]);
        float gv = tanhf(g[j + 2048]);
        float ov = sigmoidf_(g[j + 3072]);
        c = fmaf(fv, c, iv * gv);
        float d = ov * tanhf(c);
        float diff = d - inp[(size_t)(tstep + 1) * DIM + j];
        acc = fmaf(diff, diff, acc);
    }
    #pragma unroll
    for (int off = 32; off >= 1; off >>= 1) acc += __shfl_xor(acc, off);
    if ((threadIdx.x & 63) == 0) atomicAdd(mse_acc, acc);
}

__global__ __launch_bounds__(256)
void l1_reduce(const float* __restrict__ x, float* __restrict__ acc)
{
    const size_t n4 = (size_t)TSTEPS * DIM / 4;
    size_t tid = (size_t)blockIdx.x * 256 + threadIdx.x;
    size_t stride = (size_t)gridDim.x * 256;
    float s = 0.f;
    for (size_t i = tid; i < n4; i += stride) {
        float4 v = ((const float4*)x)[i];
        s += fabsf(v.x) + fabsf(v.y) + fabsf(v.z) + fabsf(v.w);
    }
    #pragma unroll
    for (int off = 32; off >= 1; off >>= 1) s += __shfl_xor(s, off);
    if ((threadIdx.x & 63) == 0) atomicAdd(acc, s);
}

__global__ void finalize(const float* __restrict__ scal, float* __restrict__ out)
{
    float mse = scal[0] / ((float)(TSTEPS - 1) * (float)DIM);
    float l1  = scal[1] / ((float)TSTEPS * (float)DIM);
    out[0] = mse + 0.25f * l1;
    out[1] = mse;
    out[2] = l1;
}

extern "C" void kernel_launch(void* const* d_in, const int* in_sizes, int n_in,
                              void* d_out, int out_size, void* d_ws, size_t ws_size,
                              hipStream_t stream)
{
    const float* inputs  = (const float*)d_in[0];
    const float* enc_Wih = (const float*)d_in[1];
    const float* enc_Whh = (const float*)d_in[2];
    const float* enc_bih = (const float*)d_in[3];
    const float* enc_bhh = (const float*)d_in[4];
    const float* dec_Wih = (const float*)d_in[5];
    const float* dec_Whh = (const float*)d_in[6];
    const float* dec_bih = (const float*)d_in[7];
    const float* dec_bhh = (const float*)d_in[8];
    float* out = (float*)d_out;

    float* ws = (float*)d_ws;
    float* gates  = ws;                          // 4096*4096 (Xenc then Gdec)
    float* signal = ws + (size_t)16777216;       // 4096*1024
    float* hsl    = ws + (size_t)20971520;       // 2 * 64*32 = 4096
    unsigned* tags = (unsigned*)(ws + (size_t)20975616); // 64*32 = 2048
    float* scal   = ws + (size_t)20977664;       // [mse, l1]
    float* mse_acc = scal + 0;
    float* l1_acc  = scal + 1;

    // zero hsl + tags + accumulators (contiguous: 4096+2048+8 floats)
    hipMemsetAsync(hsl, 0, (size_t)(4096 + 2048 + 8) * sizeof(float), stream);

    dim3 b256(256);
    // Xenc = inputs @ enc_Wih.T + enc_bih + enc_bhh
    gemm_nt<false, true><<<dim3(64, 64), b256, 0, stream>>>(
        inputs, enc_Wih, enc_bih, enc_bhh, gates, 4096, 4096, 1024);
    // sequential encoder
    encoder_scan<<<dim3(ENC_NB), b256, 0, stream>>>(
        gates, enc_Whh, signal, hsl, tags);
    // Gdec = signal[1:] @ dec_Wih.T + dec_bih + dec_bhh
    gemm_nt<false, true><<<dim3(64, 64), b256, 0, stream>>>(
        signal + DIM, dec_Wih, dec_bih, dec_bhh, gates, 4095, 4096, 1024);
    // Gdec += inputs[:-1] @ dec_Whh.T
    gemm_nt<true, false><<<dim3(64, 64), b256, 0, stream>>>(
        inputs, dec_Whh, nullptr, nullptr, gates, 4095, 4096, 1024);
    // decoder elementwise scan + mse
    decoder_scan<<<dim3(4), b256, 0, stream>>>(gates, inputs, mse_acc);
    // l1 over signal
    l1_reduce<<<dim3(256), b256, 0, stream>>>(signal, l1_acc);
    finalize<<<dim3(1), dim3(1), 0, stream>>>(scal, out);
}

// Round 3
// 13666.275 us; speedup vs baseline: 6.0937x; 4.2567x over previous
//
#include <hip/hip_runtime.h>
#include <math.h>

#define TSTEPS 4096
#define DIM 1024
#define GDIM 4096
#define ENC_NB 64

__device__ __forceinline__ float sigmoidf_(float x) {
    return 1.0f / (1.0f + expf(-x));
}

// ---------------- GEMM: C[M,N] = A[M,K] @ B[N,K]^T (+bias1+bias2) (+= if ACCUM)
template<bool ACCUM, bool BIAS>
__global__ __launch_bounds__(256)
void gemm_nt(const float* __restrict__ A, const float* __restrict__ B,
             const float* __restrict__ bias1, const float* __restrict__ bias2,
             float* __restrict__ C, int M, int N, int K)
{
    __shared__ float As[16][65];
    __shared__ float Bs[16][65];
    const int tx = threadIdx.x & 15;
    const int ty = threadIdx.x >> 4;
    const int m0 = blockIdx.y * 64;
    const int n0 = blockIdx.x * 64;
    const int lrow = threadIdx.x >> 2;       // 0..63
    const int lk4  = (threadIdx.x & 3) * 4;  // 0,4,8,12

    float acc[4][4] = {};
    for (int k0 = 0; k0 < K; k0 += 16) {
        {
            int gm = m0 + lrow;
            float4 v = make_float4(0.f, 0.f, 0.f, 0.f);
            if (gm < M) v = *(const float4*)(A + (size_t)gm * K + k0 + lk4);
            As[lk4 + 0][lrow] = v.x; As[lk4 + 1][lrow] = v.y;
            As[lk4 + 2][lrow] = v.z; As[lk4 + 3][lrow] = v.w;
            int gn = n0 + lrow;
            float4 w = *(const float4*)(B + (size_t)gn * K + k0 + lk4);
            Bs[lk4 + 0][lrow] = w.x; Bs[lk4 + 1][lrow] = w.y;
            Bs[lk4 + 2][lrow] = w.z; Bs[lk4 + 3][lrow] = w.w;
        }
        __syncthreads();
        #pragma unroll
        for (int kk = 0; kk < 16; ++kk) {
            float a[4], b[4];
            #pragma unroll
            for (int i = 0; i < 4; ++i) a[i] = As[kk][ty * 4 + i];
            #pragma unroll
            for (int j = 0; j < 4; ++j) b[j] = Bs[kk][tx * 4 + j];
            #pragma unroll
            for (int i = 0; i < 4; ++i)
                #pragma unroll
                for (int j = 0; j < 4; ++j)
                    acc[i][j] = fmaf(a[i], b[j], acc[i][j]);
        }
        __syncthreads();
    }
    #pragma unroll
    for (int i = 0; i < 4; ++i) {
        int gm = m0 + ty * 4 + i;
        if (gm >= M) continue;
        #pragma unroll
        for (int j = 0; j < 4; ++j) {
            int gn = n0 + tx * 4 + j;
            float v = acc[i][j];
            if (BIAS) v += bias1[gn] + bias2[gn];
            size_t idx = (size_t)gm * N + gn;
            if (ACCUM) v += C[idx];
            C[idx] = v;
        }
    }
}

// ---------------- Encoder sequential scan.
// 64 blocks x 1024 threads. Block b owns h-channels [b*16, b*16+16) and gate
// rows {q*1024 + b*16 + hi}. Thread t: row r=t>>4 (0..63), k-chunk sub=t&15
// (64 floats). Whh slice lives in registers (16 float4 / thread).
// h exchange: slots[step&1][j] is one 8B word = (tag<<32)|bits(h_j). One
// relaxed agent-scope store to publish, one polled load to consume — tag and
// payload arrive together, no fences, single round trip.
__global__ __launch_bounds__(1024)
void encoder_scan(const float* __restrict__ Xg,   // [4096][4096] x@Wih.T + biases
                  const float* __restrict__ Whh,  // [4096][1024]
                  float* __restrict__ signal,     // [4096][1024]
                  unsigned long long* __restrict__ slots) // [2][1024], zeroed
{
    const int b = blockIdx.x;
    const int t = threadIdx.x;
    const int hbase = b * 16;
    const int r = t >> 4, sub = t & 15;
    const int q = r >> 4, hi = r & 15;
    const int grow = q * 1024 + hbase + hi;

    // load this thread's 64 weights into registers
    float4 w[16];
    {
        const float4* wrow = (const float4*)(Whh + (size_t)grow * 1024 + sub * 64);
        #pragma unroll
        for (int i = 0; i < 16; ++i) w[i] = wrow[i];
    }

    __shared__ float hls[16 * 68];   // chunk-major, stride 68 (2-way max)
    __shared__ float gl[4][16];
    __shared__ float cs[16];
    if (t < 16) cs[t] = 0.f;
    __syncthreads();

    for (int step = 0; step < TSTEPS; ++step) {
        // prefetch this step's Xg entry (hides under the poll)
        float xg = 0.f;
        if (sub == 0) xg = Xg[(size_t)step * GDIM + grow];

        // single-round-trip consume: poll own slot, payload rides with tag
        unsigned long long v;
        {
            const unsigned long long* sp = slots + (size_t)(step & 1) * 1024 + t;
            while (true) {
                v = __hip_atomic_load(sp, __ATOMIC_RELAXED, __HIP_MEMORY_SCOPE_AGENT);
                if ((unsigned)(v >> 32) >= (unsigned)step) break;
                __builtin_amdgcn_s_sleep(1);
            }
        }
        hls[(t >> 6) * 68 + (t & 63)] = __uint_as_float((unsigned)v);
        __syncthreads();

        // dot: 64 register FMAs against LDS h chunk
        float s = 0.f;
        const float* hv = hls + sub * 68;
        #pragma unroll
        for (int i = 0; i < 16; ++i) {
            float4 h4 = *(const float4*)(hv + i * 4);
            s = fmaf(w[i].x, h4.x, s); s = fmaf(w[i].y, h4.y, s);
            s = fmaf(w[i].z, h4.z, s); s = fmaf(w[i].w, h4.w, s);
        }
        s += __shfl_xor(s, 1);
        s += __shfl_xor(s, 2);
        s += __shfl_xor(s, 4);
        s += __shfl_xor(s, 8);
        if (sub == 0) gl[q][hi] = s + xg;
        __syncthreads();

        if (t < 16) {
            float iv = sigmoidf_(gl[0][t]);
            float fv = sigmoidf_(gl[1][t]);
            float gv = tanhf(gl[2][t]);
            float ov = sigmoidf_(gl[3][t]);
            float c = fmaf(fv, cs[t], iv * gv);
            cs[t] = c;
            float h = ov * tanhf(c);
            signal[(size_t)step * DIM + hbase + t] = h;
            unsigned long long pv =
                ((unsigned long long)(unsigned)(step + 1) << 32) | __float_as_uint(h);
            __hip_atomic_store(slots + (size_t)((step + 1) & 1) * 1024 + hbase + t,
                               pv, __ATOMIC_RELAXED, __HIP_MEMORY_SCOPE_AGENT);
        }
        // no barrier needed here: next-step hls writes are gated by the
        // next first __syncthreads; publisher threads join it after storing.
    }
}

// ---------------- Decoder: c-recurrence is elementwise per channel -> 1024
// independent scans. decoded[t] = o*tanh(c); accumulate sum of squared error.
__global__ __launch_bounds__(256)
void decoder_scan(const float* __restrict__ G,    // [4095][4096] full gate preacts
                  const float* __restrict__ inp,  // [4096][1024]
                  float* __restrict__ mse_acc)
{
    const int j = blockIdx.x * 256 + threadIdx.x; // 0..1023
    float c = 0.f, acc = 0.f;
    for (int tstep = 0; tstep < TSTEPS - 1; ++tstep) {
        const float* g = G + (size_t)tstep * GDIM;
        float iv = sigmoidf_(g[j]);
        float fv = sigmoidf_(g[j + 1024]);
        float gv = tanhf(g[j + 2048]);
        float ov = sigmoidf_(g[j + 3072]);
        c = fmaf(fv, c, iv * gv);
        float d = ov * tanhf(c);
        float diff = d - inp[(size_t)(tstep + 1) * DIM + j];
        acc = fmaf(diff, diff, acc);
    }
    #pragma unroll
    for (int off = 32; off >= 1; off >>= 1) acc += __shfl_xor(acc, off);
    if ((threadIdx.x & 63) == 0) atomicAdd(mse_acc, acc);
}

__global__ __launch_bounds__(256)
void l1_reduce(const float* __restrict__ x, float* __restrict__ acc)
{
    const size_t n4 = (size_t)TSTEPS * DIM / 4;
    size_t tid = (size_t)blockIdx.x * 256 + threadIdx.x;
    size_t stride = (size_t)gridDim.x * 256;
    float s = 0.f;
    for (size_t i = tid; i < n4; i += stride) {
        float4 v = ((const float4*)x)[i];
        s += fabsf(v.x) + fabsf(v.y) + fabsf(v.z) + fabsf(v.w);
    }
    #pragma unroll
    for (int off = 32; off >= 1; off >>= 1) s += __shfl_xor(s, off);
    if ((threadIdx.x & 63) == 0) atomicAdd(acc, s);
}

__global__ void finalize(const float* __restrict__ scal, float* __restrict__ out)
{
    float mse = scal[0] / ((float)(TSTEPS - 1) * (float)DIM);
    float l1  = scal[1] / ((float)TSTEPS * (float)DIM);
    out[0] = mse + 0.25f * l1;
    out[1] = mse;
    out[2] = l1;
}

extern "C" void kernel_launch(void* const* d_in, const int* in_sizes, int n_in,
                              void* d_out, int out_size, void* d_ws, size_t ws_size,
                              hipStream_t stream)
{
    const float* inputs  = (const float*)d_in[0];
    const float* enc_Wih = (const float*)d_in[1];
    const float* enc_Whh = (const float*)d_in[2];
    const float* enc_bih = (const float*)d_in[3];
    const float* enc_bhh = (const float*)d_in[4];
    const float* dec_Wih = (const float*)d_in[5];
    const float* dec_Whh = (const float*)d_in[6];
    const float* dec_bih = (const float*)d_in[7];
    const float* dec_bhh = (const float*)d_in[8];
    float* out = (float*)d_out;

    float* ws = (float*)d_ws;
    float* gates  = ws;                          // 4096*4096 (Xenc then Gdec)
    float* signal = ws + (size_t)16777216;       // 4096*1024
    unsigned long long* slots = (unsigned long long*)(ws + (size_t)20971520); // 2*1024 u64
    float* scal   = ws + (size_t)20975616;       // [mse, l1]
    float* mse_acc = scal + 0;
    float* l1_acc  = scal + 1;

    // zero slots (16KB) + accumulators
    hipMemsetAsync(slots, 0, 2 * 1024 * sizeof(unsigned long long) + 32, stream);

    dim3 b256(256);
    // Xenc = inputs @ enc_Wih.T + enc_bih + enc_bhh
    gemm_nt<false, true><<<dim3(64, 64), b256, 0, stream>>>(
        inputs, enc_Wih, enc_bih, enc_bhh, gates, 4096, 4096, 1024);
    // sequential encoder
    encoder_scan<<<dim3(ENC_NB), dim3(1024), 0, stream>>>(
        gates, enc_Whh, signal, slots);
    // Gdec = signal[1:] @ dec_Wih.T + dec_bih + dec_bhh
    gemm_nt<false, true><<<dim3(64, 64), b256, 0, stream>>>(
        signal + DIM, dec_Wih, dec_bih, dec_bhh, gates, 4095, 4096, 1024);
    // Gdec += inputs[:-1] @ dec_Whh.T
    gemm_nt<true, false><<<dim3(64, 64), b256, 0, stream>>>(
        inputs, dec_Whh, nullptr, nullptr, gates, 4095, 4096, 1024);
    // decoder elementwise scan + mse
    decoder_scan<<<dim3(4), b256, 0, stream>>>(gates, inputs, mse_acc);
    // l1 over signal
    l1_reduce<<<dim3(256), b256, 0, stream>>>(signal, l1_acc);
    finalize<<<dim3(1), dim3(1), 0, stream>>>(scal, out);
}

// Round 4
// 9081.831 us; speedup vs baseline: 9.1698x; 1.5048x over previous
//
#include <hip/hip_runtime.h>
#include <math.h>

#define TSTEPS 4096
#define DIM 1024
#define GDIM 4096
#define ENC_NB 64
#define NSEG 64
#define SEGLEN 64

typedef short bf16x8 __attribute__((ext_vector_type(8)));
typedef float f32x4 __attribute__((ext_vector_type(4)));
typedef unsigned int uint4v __attribute__((ext_vector_type(4)));

__device__ __forceinline__ float sigmoidf_(float x) {
    return 1.0f / (1.0f + expf(-x));
}

// Load 8 consecutive fp32, split each into bf16 hi (truncate) + bf16 lo
// (truncated residual). x ~= hi + lo to ~2^-15 relative.
__device__ __forceinline__ void loadcvt(const float* __restrict__ p,
                                        bf16x8& hi, bf16x8& lo)
{
    float4 a = *(const float4*)p;
    float4 b = *(const float4*)(p + 4);
    float f[8] = {a.x, a.y, a.z, a.w, b.x, b.y, b.z, b.w};
    uint4v hw, lw;
    #pragma unroll
    for (int j = 0; j < 4; ++j) {
        unsigned u0 = __float_as_uint(f[2*j]);
        unsigned u1 = __float_as_uint(f[2*j+1]);
        unsigned m0 = u0 & 0xffff0000u;
        unsigned m1 = u1 & 0xffff0000u;
        float r0 = f[2*j]   - __uint_as_float(m0);
        float r1 = f[2*j+1] - __uint_as_float(m1);
        // packed hi16s: result = {u1[31:16], u0[31:16]}
        hw[j] = __builtin_amdgcn_perm(u1, u0, 0x07060302u);
        lw[j] = __builtin_amdgcn_perm(__float_as_uint(r1), __float_as_uint(r0),
                                      0x07060302u);
    }
    hi = __builtin_bit_cast(bf16x8, hw);
    lo = __builtin_bit_cast(bf16x8, lw);
}

// C[M,N] = A1[M,K]·B1[N,K]^T (+ A2·B2^T if DUAL) + bias1 + bias2
// K = 1024 fixed. Tile 128x128, 4 waves of 64x64, 16x16x32 bf16 MFMA,
// split-precision (hi/lo) => 3 MFMAs per fragment pair.
template<bool DUAL>
__global__ __launch_bounds__(256)
void gemm_split(const float* __restrict__ A1, const float* __restrict__ B1,
                const float* __restrict__ A2, const float* __restrict__ B2,
                const float* __restrict__ bias1, const float* __restrict__ bias2,
                float* __restrict__ C, int N)
{
    const int lane = threadIdx.x & 63;
    const int wid  = threadIdx.x >> 6;
    const int m0 = blockIdx.y * 128 + (wid >> 1) * 64;
    const int n0 = blockIdx.x * 128 + (wid & 1) * 64;
    const int rA   = m0 + (lane & 15);
    const int cB   = n0 + (lane & 15);
    const int koff = (lane >> 4) * 8;

    f32x4 acc[4][4] = {};

    const int npass = DUAL ? 2 : 1;
    for (int pass = 0; pass < npass; ++pass) {
        const float* __restrict__ A = (DUAL && pass) ? A2 : A1;
        const float* __restrict__ B = (DUAL && pass) ? B2 : B1;
        for (int k0 = 0; k0 < 1024; k0 += 32) {
            bf16x8 ah[4], al[4], bh[4], bl[4];
            #pragma unroll
            for (int i = 0; i < 4; ++i)
                loadcvt(A + (size_t)(rA + i * 16) * 1024 + k0 + koff, ah[i], al[i]);
            #pragma unroll
            for (int j = 0; j < 4; ++j)
                loadcvt(B + (size_t)(cB + j * 16) * 1024 + k0 + koff, bh[j], bl[j]);
            #pragma unroll
            for (int i = 0; i < 4; ++i)
                #pragma unroll
                for (int j = 0; j < 4; ++j) {
                    acc[i][j] = __builtin_amdgcn_mfma_f32_16x16x32_bf16(
                        ah[i], bh[j], acc[i][j], 0, 0, 0);
                    acc[i][j] = __builtin_amdgcn_mfma_f32_16x16x32_bf16(
                        ah[i], bl[j], acc[i][j], 0, 0, 0);
                    acc[i][j] = __builtin_amdgcn_mfma_f32_16x16x32_bf16(
                        al[i], bh[j], acc[i][j], 0, 0, 0);
                }
        }
    }

    // C/D frag layout: col = lane&15, row = (lane>>4)*4 + r
    const int er = (lane >> 4) * 4;
    const int ec = lane & 15;
    #pragma unroll
    for (int j = 0; j < 4; ++j) {
        int col = n0 + j * 16 + ec;
        float bb = bias1[col] + bias2[col];
        #pragma unroll
        for (int i = 0; i < 4; ++i) {
            int rowb = m0 + i * 16 + er;
            #pragma unroll
            for (int r = 0; r < 4; ++r)
                C[(size_t)(rowb + r) * N + col] = acc[i][j][r] + bb;
        }
    }
}

// ---------------- Encoder sequential scan (unchanged from round 3).
__global__ __launch_bounds__(1024)
void encoder_scan(const float* __restrict__ Xg,   // [4096][4096]
                  const float* __restrict__ Whh,  // [4096][1024]
                  float* __restrict__ signal,     // [4097][1024]
                  unsigned long long* __restrict__ slots) // [2][1024], zeroed
{
    const int b = blockIdx.x;
    const int t = threadIdx.x;
    const int hbase = b * 16;
    const int r = t >> 4, sub = t & 15;
    const int q = r >> 4, hi = r & 15;
    const int grow = q * 1024 + hbase + hi;

    float4 w[16];
    {
        const float4* wrow = (const float4*)(Whh + (size_t)grow * 1024 + sub * 64);
        #pragma unroll
        for (int i = 0; i < 16; ++i) w[i] = wrow[i];
    }

    __shared__ float hls[16 * 68];
    __shared__ float gl[4][16];
    __shared__ float cs[16];
    if (t < 16) cs[t] = 0.f;
    __syncthreads();

    for (int step = 0; step < TSTEPS; ++step) {
        float xg = 0.f;
        if (sub == 0) xg = Xg[(size_t)step * GDIM + grow];

        unsigned long long v;
        {
            const unsigned long long* sp = slots + (size_t)(step & 1) * 1024 + t;
            while (true) {
                v = __hip_atomic_load(sp, __ATOMIC_RELAXED, __HIP_MEMORY_SCOPE_AGENT);
                if ((unsigned)(v >> 32) >= (unsigned)step) break;
                __builtin_amdgcn_s_sleep(1);
            }
        }
        hls[(t >> 6) * 68 + (t & 63)] = __uint_as_float((unsigned)v);
        __syncthreads();

        float s = 0.f;
        const float* hv = hls + sub * 68;
        #pragma unroll
        for (int i = 0; i < 16; ++i) {
            float4 h4 = *(const float4*)(hv + i * 4);
            s = fmaf(w[i].x, h4.x, s); s = fmaf(w[i].y, h4.y, s);
            s = fmaf(w[i].z, h4.z, s); s = fmaf(w[i].w, h4.w, s);
        }
        s += __shfl_xor(s, 1);
        s += __shfl_xor(s, 2);
        s += __shfl_xor(s, 4);
        s += __shfl_xor(s, 8);
        if (sub == 0) gl[q][hi] = s + xg;
        __syncthreads();

        if (t < 16) {
            float iv = sigmoidf_(gl[0][t]);
            float fv = sigmoidf_(gl[1][t]);
            float gv = tanhf(gl[2][t]);
            float ov = sigmoidf_(gl[3][t]);
            float c = fmaf(fv, cs[t], iv * gv);
            cs[t] = c;
            float h = ov * tanhf(c);
            signal[(size_t)step * DIM + hbase + t] = h;
            unsigned long long pv =
                ((unsigned long long)(unsigned)(step + 1) << 32) | __float_as_uint(h);
            __hip_atomic_store(slots + (size_t)((step + 1) & 1) * 1024 + hbase + t,
                               pv, __ATOMIC_RELAXED, __HIP_MEMORY_SCOPE_AGENT);
        }
    }
}

// ---------------- Decoder: segmented affine scan. c_t = f_t*c + (i_t*g_t).
// Phase A: per (segment, channel) compose A = prod f, B = accumulated drive.
__global__ __launch_bounds__(256)
void dec_compose(const float* __restrict__ G, float* __restrict__ Aseg,
                 float* __restrict__ Bseg)
{
    const int j = blockIdx.x * 256 + threadIdx.x;
    const int s = blockIdx.y;
    const int t0 = s * SEGLEN;
    const int t1 = min(t0 + SEGLEN, TSTEPS - 1);
    float A = 1.f, Bv = 0.f;
    for (int t = t0; t < t1; ++t) {
        const float* g = G + (size_t)t * GDIM;
        float iv = sigmoidf_(g[j]);
        float fv = sigmoidf_(g[j + 1024]);
        float gv = tanhf(g[j + 2048]);
        A *= fv;
        Bv = fmaf(fv, Bv, iv * gv);
    }
    Aseg[s * DIM + j] = A;
    Bseg[s * DIM + j] = Bv;
}

// Phase B: tiny inter-segment scan (c at each segment start).
__global__ __launch_bounds__(1024)
void dec_scan(const float* __restrict__ Aseg, const float* __restrict__ Bseg,
              float* __restrict__ cinit)
{
    const int j = threadIdx.x;
    float c = 0.f;
    for (int s = 0; s < NSEG; ++s) {
        cinit[s * DIM + j] = c;
        c = fmaf(Aseg[s * DIM + j], c, Bseg[s * DIM + j]);
    }
}

// Phase C: re-emit within segment, accumulate squared error.
__global__ __launch_bounds__(256)
void dec_emit(const float* __restrict__ G, const float* __restrict__ inp,
              const float* __restrict__ cinit, float* __restrict__ mse_acc)
{
    const int j = blockIdx.x * 256 + threadIdx.x;
    const int s = blockIdx.y;
    const int t0 = s * SEGLEN;
    const int t1 = min(t0 + SEGLEN, TSTEPS - 1);
    float c = cinit[s * DIM + j];
    float acc = 0.f;
    for (int t = t0; t < t1; ++t) {
        const float* g = G + (size_t)t * GDIM;
        float iv = sigmoidf_(g[j]);
        float fv = sigmoidf_(g[j + 1024]);
        float gv = tanhf(g[j + 2048]);
        float ov = sigmoidf_(g[j + 3072]);
        c = fmaf(fv, c, iv * gv);
        float d = ov * tanhf(c);
        float diff = d - inp[(size_t)(t + 1) * DIM + j];
        acc = fmaf(diff, diff, acc);
    }
    #pragma unroll
    for (int off = 32; off >= 1; off >>= 1) acc += __shfl_xor(acc, off);
    if ((threadIdx.x & 63) == 0) atomicAdd(mse_acc, acc);
}

__global__ __launch_bounds__(256)
void l1_reduce(const float* __restrict__ x, float* __restrict__ acc)
{
    const size_t n4 = (size_t)TSTEPS * DIM / 4;
    size_t tid = (size_t)blockIdx.x * 256 + threadIdx.x;
    size_t stride = (size_t)gridDim.x * 256;
    float s = 0.f;
    for (size_t i = tid; i < n4; i += stride) {
        float4 v = ((const float4*)x)[i];
        s += fabsf(v.x) + fabsf(v.y) + fabsf(v.z) + fabsf(v.w);
    }
    #pragma unroll
    for (int off = 32; off >= 1; off >>= 1) s += __shfl_xor(s, off);
    if ((threadIdx.x & 63) == 0) atomicAdd(acc, s);
}

__global__ void finalize(const float* __restrict__ scal, float* __restrict__ out)
{
    float mse = scal[0] / ((float)(TSTEPS - 1) * (float)DIM);
    float l1  = scal[1] / ((float)TSTEPS * (float)DIM);
    out[0] = mse + 0.25f * l1;
    out[1] = mse;
    out[2] = l1;
}

extern "C" void kernel_launch(void* const* d_in, const int* in_sizes, int n_in,
                              void* d_out, int out_size, void* d_ws, size_t ws_size,
                              hipStream_t stream)
{
    const float* inputs  = (const float*)d_in[0];
    const float* enc_Wih = (const float*)d_in[1];
    const float* enc_Whh = (const float*)d_in[2];
    const float* enc_bih = (const float*)d_in[3];
    const float* enc_bhh = (const float*)d_in[4];
    const float* dec_Wih = (const float*)d_in[5];
    const float* dec_Whh = (const float*)d_in[6];
    const float* dec_bih = (const float*)d_in[7];
    const float* dec_bhh = (const float*)d_in[8];
    float* out = (float*)d_out;

    float* ws = (float*)d_ws;
    float* gates  = ws;                            // [4096][4096] Xenc then Gdec
    float* signal = ws + (size_t)16777216;         // [4097][1024] (row 4096 zero)
    unsigned long long* slots =
        (unsigned long long*)(ws + (size_t)20972544);   // [2][1024] u64
    float* scal   = ws + (size_t)20976640;         // [mse, l1] + pad
    float* Aseg   = ws + (size_t)20976648;         // [64][1024]
    float* Bseg   = ws + (size_t)21042184;         // [64][1024]
    float* cinit  = ws + (size_t)21107720;         // [64][1024]
    float* mse_acc = scal + 0;
    float* l1_acc  = scal + 1;

    // one memset: signal row 4096 (1024 f) + slots (4096 f) + scal (8 f)
    hipMemsetAsync(ws + (size_t)20971520, 0, (size_t)(1024 + 4096 + 8) * 4, stream);

    dim3 b256(256);
    // Xenc = inputs @ enc_Wih^T + enc_bih + enc_bhh   (split-bf16 MFMA)
    gemm_split<false><<<dim3(32, 32), b256, 0, stream>>>(
        inputs, enc_Wih, nullptr, nullptr, enc_bih, enc_bhh, gates, GDIM);
    // sequential encoder
    encoder_scan<<<dim3(ENC_NB), dim3(1024), 0, stream>>>(
        gates, enc_Whh, signal, slots);
    // Gdec = signal[1:] @ dec_Wih^T + inputs @ dec_Whh^T + dec biases (fused)
    gemm_split<true><<<dim3(32, 32), b256, 0, stream>>>(
        signal + DIM, dec_Wih, inputs, dec_Whh, dec_bih, dec_bhh, gates, GDIM);
    // decoder segmented scan + mse
    dec_compose<<<dim3(4, NSEG), b256, 0, stream>>>(gates, Aseg, Bseg);
    dec_scan<<<dim3(1), dim3(1024), 0, stream>>>(Aseg, Bseg, cinit);
    dec_emit<<<dim3(4, NSEG), b256, 0, stream>>>(gates, inputs, cinit, mse_acc);
    // l1 over signal
    l1_reduce<<<dim3(256), b256, 0, stream>>>(signal, l1_acc);
    finalize<<<dim3(1), dim3(1), 0, stream>>>(scal, out);
}